// Round 12
// baseline (165.097 us; speedup 1.0000x reference)
//
#include <hip/hip_runtime.h>
#include <math.h>

#define NN 10000
#define NE 160000

typedef __attribute__((ext_vector_type(8))) short s8v;
typedef __attribute__((ext_vector_type(4))) float f4v;
typedef unsigned short u16;

// ---- ws byte layout ----
#define OFF_P1HB 0u          // N*32 bf16      = 640000 B
#define OFF_P3HB 640000u     // N*3*32 bf16    = 1920000 B
#define OFF_WB   2560000u    // NWB bf16       = 184320 B
#define OFF_P1N  2764800u    // N*32 f32       = 1280000 B
#define OFF_P3N  4044800u    // N*3*32 f32     = 3840000 B

// ---- wb (ushort element) offsets: ALL tables in per-lane consumption order
// [..][lane 64][8 u16] so every wave B-load is one contiguous 1KB read. ----
#define OW1T1 0       // [nt2][ks2][64][8]  = 2048
#define OW2T1 2048    // [nt6][64][8]       = 3072
#define OII1T 5120    // [nt2][64][8]       = 1024
#define OW1T3 6144    // [nt2][ks2][64][8]  = 2048
#define OW2T3 8192    // [nt2][64][8]       = 1024
#define OII3T 9216    // [nt2][64][8]       = 1024
#define OBLG  10240   // [b8][nt6][ks3][64][8] = 73728  (18432 B per b)
#define OBL3G 83968   // [b8][nt2][64][8]   = 8192     (16384 B total)
#define NWB   92160

__device__ __forceinline__ short f2b(float f) {
    unsigned u = __float_as_uint(f);
    u += 0x7fffu + ((u >> 16) & 1u);
    return (short)(u >> 16);
}
__device__ __forceinline__ float tanhf_fast(float x) {
    float xc = fminf(9.f, fmaxf(-9.f, x));
    float e = __expf(2.f * xc);
    return (e - 1.f) * __builtin_amdgcn_rcpf(e + 1.f);
}

// ---------------- node prep: p1h/p3h = tanh(x@W+b) -> bf16 ----------------
__global__ __launch_bounds__(256) void node_prep(
    const float* __restrict__ p1, const float* __restrict__ p3,
    const float* __restrict__ pp1_W, const float* __restrict__ pp1_b,
    const float* __restrict__ pp3_W, const float* __restrict__ pp3_b,
    u16* __restrict__ p1hb, u16* __restrict__ p3hb)
{
    __shared__ float Ws[2][32 * 32];
    __shared__ float bsm[2][32];
    int tid = threadIdx.x;
    for (int i = tid; i < 32 * 32; i += 256) { Ws[0][i] = pp1_W[i]; Ws[1][i] = pp3_W[i]; }
    if (tid < 32) { bsm[0][tid] = pp1_b[tid]; bsm[1][tid] = pp3_b[tid]; }
    __syncthreads();
    int idx = blockIdx.x * 256 + tid;
    int n = idx >> 7;
    int r = (idx >> 5) & 3;
    int c = idx & 31;
    int sel = (r == 0) ? 0 : 1;
    const float* in = (r == 0) ? (p1 + n * 32) : (p3 + (n * 3 + (r - 1)) * 32);
    float acc = bsm[sel][c];
    #pragma unroll
    for (int k = 0; k < 32; ++k) acc += in[k] * Ws[sel][k * 32 + c];
    short v = f2b(tanhf(acc));
    if (r == 0) p1hb[n * 32 + c] = (u16)v;
    else        p3hb[(n * 3 + (r - 1)) * 32 + c] = (u16)v;
}

// -------- weight prep: bf16 + per-lane-consumption-order layout -----------
__global__ __launch_bounds__(256) void wprep(
    const float* __restrict__ W1, const float* __restrict__ W2,
    const float* __restrict__ W3, const float* __restrict__ ii1,
    const float* __restrict__ W13, const float* __restrict__ W23,
    const float* __restrict__ W33, const float* __restrict__ ii3,
    u16* __restrict__ wb)
{
    int i0 = blockIdx.x * 256 + threadIdx.x;
    if (i0 >= NWB) return;
    int i = i0;
    float v;
    if (i < 2048) {
        int j = i & 7, L = (i >> 3) & 63, ks = (i >> 9) & 1, nt = i >> 10;
        v = W1[(ks * 32 + (L >> 4) * 8 + j) * 32 + 16 * nt + (L & 15)];
    } else if ((i -= 2048) < 3072) {
        int j = i & 7, L = (i >> 3) & 63, nt = i >> 9;
        v = W2[((L >> 4) * 8 + j) * 96 + 16 * nt + (L & 15)];
    } else if ((i -= 3072) < 1024) {
        int j = i & 7, L = (i >> 3) & 63, nt = i >> 9;
        v = ii1[((L >> 4) * 8 + j) * 32 + 16 * nt + (L & 15)];
    } else if ((i -= 1024) < 2048) {
        int j = i & 7, L = (i >> 3) & 63, ks = (i >> 9) & 1, nt = i >> 10;
        v = W13[(ks * 32 + (L >> 4) * 8 + j) * 32 + 16 * nt + (L & 15)];
    } else if ((i -= 2048) < 1024) {
        int j = i & 7, L = (i >> 3) & 63, nt = i >> 9;
        v = W23[((L >> 4) * 8 + j) * 32 + 16 * nt + (L & 15)];
    } else if ((i -= 1024) < 1024) {
        int j = i & 7, L = (i >> 3) & 63, nt = i >> 9;
        v = ii3[((L >> 4) * 8 + j) * 32 + 16 * nt + (L & 15)];
    } else if ((i -= 1024) < 73728) {
        int b = i / 9216, r = i % 9216;
        int nt = r / 1536, r2 = r % 1536;
        int ks = r2 / 512, r3 = r2 & 511;
        int L = r3 >> 3, j = r3 & 7;
        v = W3[(ks * 32 + (L >> 4) * 8 + j) * 768 + (16 * nt + (L & 15)) * 8 + b];
    } else {
        i -= 73728;
        int b = i >> 10, r = i & 1023;
        int nt = r >> 9, r3 = r & 511;
        int L = r3 >> 3, j = r3 & 7;
        v = W33[((L >> 4) * 8 + j) * 256 + (16 * nt + (L & 15)) * 8 + b];
    }
    wb[i0] = (u16)f2b(v);
}

// --- fused edge kernel: 4 waves x 32 edges (M=2), LDS-shared B operand ----
// Bl (18.4 KB/b-chunk) is cooperatively staged & shared by the 4 waves:
// block reads weights ONCE (~170 KB) vs per-wave L2 re-reads (~1.3 MB).
// Inner-loop B reads: lane l at byte l*16 -> conflict-free ds_read_b128.
// LDS 43.5 KB -> 3 blocks/CU (launch_bounds(256,3), VGPR cap 170 >> ~110).
__global__ __launch_bounds__(256, 3) void edge_kernel(
    const u16* __restrict__ p1hb, const u16* __restrict__ p3hb,
    const float* __restrict__ r3, const float* __restrict__ basis,
    const int* __restrict__ idx_i, const int* __restrict__ idx_j,
    const u16* __restrict__ wb,
    const float* __restrict__ b1, const float* __restrict__ b2,
    const float* __restrict__ ii1b,
    const float* __restrict__ b13, const float* __restrict__ b23,
    const float* __restrict__ ii3b,
    float* __restrict__ p1n, float* __restrict__ p3n)
{
    __shared__ int4 smem4[43520 / 16];
    char* sm  = (char*)smem4;
    u16*  sBl = (u16*)sm;                              // 18432 B shared B-stage
    char* sw  = sm + 18432 + ((threadIdx.x >> 6) * 6272);
    int*   sIdxI = (int*)(sw + 0);       // [32]
    int*   sIdxJ = (int*)(sw + 128);     // [32]
    float* sBasT = (float*)(sw + 256);   // [8][32]
    float* sR3   = (float*)(sw + 1280);  // [3][32]
    u16*   sT1   = (u16*)(sw + 1664);    // [16][104]
    u16*   sT2   = (u16*)(sw + 4992);    // [16][40]

    const int tid = threadIdx.x;
    const int w   = tid >> 6;
    const int l   = tid & 63;
    const int r16 = l & 15;
    const int kg  = l >> 4;
    const int ebase = blockIdx.x * 128 + w * 32;

    // ---- per-wave meta staging ----
    if (l < 32) sIdxI[l] = idx_i[ebase + l];
    else        sIdxJ[l - 32] = idx_j[ebase + l - 32];
    {
        int e = l & 31, hf = l >> 5;
        float4 q = ((const float4*)(basis + (size_t)(ebase + e) * 8))[hf];
        sBasT[(4 * hf + 0) * 32 + e] = q.x;
        sBasT[(4 * hf + 1) * 32 + e] = q.y;
        sBasT[(4 * hf + 2) * 32 + e] = q.z;
        sBasT[(4 * hf + 3) * 32 + e] = q.w;
        if (hf == 0) {
            sR3[e]      = r3[(size_t)(ebase + e) * 3 + 0];
            sR3[32 + e] = r3[(size_t)(ebase + e) * 3 + 1];
            sR3[64 + e] = r3[(size_t)(ebase + e) * 3 + 2];
        }
    }

    const float vb1[2]  = { b1[r16],   b1[16 + r16] };
    float vb2[6];
    #pragma unroll
    for (int nt = 0; nt < 6; ++nt) vb2[nt] = b2[16 * nt + r16];
    const float vii1[2] = { ii1b[r16], ii1b[16 + r16] };
    const float vb13[2] = { b13[r16],  b13[16 + r16] };
    const float vb23[2] = { b23[r16],  b23[16 + r16] };
    const float vii3[2] = { ii3b[r16], ii3b[16 + r16] };

    const f4v zf = {0.f, 0.f, 0.f, 0.f};

    // ---- Phase A: per M-tile pi1 front (h1 -> h2 -> af regs) ----
    s8v af[2][3];
    f4v accT[2][6];
    #pragma unroll
    for (int m = 0; m < 2; ++m)
        #pragma unroll
        for (int nt = 0; nt < 6; ++nt) accT[m][nt] = zf;

    {
        const u16* gW1 = wb + OW1T1;
        const u16* gW2 = wb + OW2T1;
        #pragma unroll
        for (int m = 0; m < 2; ++m) {
            int rowA = m * 16 + r16;
            int ni = sIdxI[rowA], nj = sIdxJ[rowA];
            s8v av0 = *(const s8v*)(p1hb + (size_t)ni * 32 + kg * 8);
            s8v av1 = *(const s8v*)(p1hb + (size_t)nj * 32 + kg * 8);
            #pragma unroll
            for (int nt = 0; nt < 2; ++nt) {
                s8v bv0 = *(const s8v*)(gW1 + ((nt * 2 + 0) * 64 + l) * 8);
                s8v bv1 = *(const s8v*)(gW1 + ((nt * 2 + 1) * 64 + l) * 8);
                f4v a = __builtin_amdgcn_mfma_f32_16x16x32_bf16(av0, bv0, zf, 0, 0, 0);
                a = __builtin_amdgcn_mfma_f32_16x16x32_bf16(av1, bv1, a, 0, 0, 0);
                #pragma unroll
                for (int rr = 0; rr < 4; ++rr)
                    sT2[(4 * kg + rr) * 40 + 16 * nt + r16] = (u16)f2b(a[rr] + vb1[nt]);
            }
            s8v av2 = *(const s8v*)(sT2 + r16 * 40 + 8 * kg);
            #pragma unroll
            for (int nt = 0; nt < 6; ++nt) {
                s8v bv = *(const s8v*)(gW2 + (nt * 64 + l) * 8);
                f4v acc = __builtin_amdgcn_mfma_f32_16x16x32_bf16(av2, bv, zf, 0, 0, 0);
                #pragma unroll
                for (int rr = 0; rr < 4; ++rr)
                    sT1[(4 * kg + rr) * 104 + 16 * nt + r16] = (u16)f2b(acc[rr] + vb2[nt]);
            }
            af[m][0] = *(const s8v*)(sT1 + r16 * 104 + 8 * kg);
            af[m][1] = *(const s8v*)(sT1 + r16 * 104 + 32 + 8 * kg);
            af[m][2] = *(const s8v*)(sT1 + r16 * 104 + 64 + 8 * kg);
        }
    }

    // ---- Phase B: pi1-W3 b-form; Bl staged chunk-by-chunk through LDS ----
    {
        const int4* gBl2 = (const int4*)(wb + OBLG);   // 1152 int4 per b-chunk
        int4 tmp[5];
        #pragma unroll
        for (int i = 0; i < 5; ++i) {
            int r = w + 4 * i;
            if (r < 18) tmp[i] = gBl2[r * 64 + l];
        }
        for (int b = 0; b < 8; ++b) {
            __syncthreads();                       // prev-chunk readers done
            #pragma unroll
            for (int i = 0; i < 5; ++i) {
                int r = w + 4 * i;
                if (r < 18) ((int4*)sBl)[r * 64 + l] = tmp[i];
            }
            __syncthreads();                       // chunk visible to all
            if (b < 7) {
                #pragma unroll
                for (int i = 0; i < 5; ++i) {
                    int r = w + 4 * i;
                    if (r < 18) tmp[i] = gBl2[(size_t)(b + 1) * 1152 + r * 64 + l];
                }
            }
            float tb[2][4];
            #pragma unroll
            for (int m = 0; m < 2; ++m)
                #pragma unroll
                for (int rr = 0; rr < 4; ++rr)
                    tb[m][rr] = sBasT[b * 32 + m * 16 + 4 * kg + rr];
            #pragma unroll
            for (int nt = 0; nt < 6; ++nt) {
                s8v bv0 = *(const s8v*)(sBl + ((nt * 3 + 0) * 64 + l) * 8);
                s8v bv1 = *(const s8v*)(sBl + ((nt * 3 + 1) * 64 + l) * 8);
                s8v bv2 = *(const s8v*)(sBl + ((nt * 3 + 2) * 64 + l) * 8);
                #pragma unroll
                for (int m = 0; m < 2; ++m) {
                    f4v D = __builtin_amdgcn_mfma_f32_16x16x32_bf16(af[m][0], bv0, zf, 0, 0, 0);
                    D = __builtin_amdgcn_mfma_f32_16x16x32_bf16(af[m][1], bv1, D, 0, 0, 0);
                    D = __builtin_amdgcn_mfma_f32_16x16x32_bf16(af[m][2], bv2, D, 0, 0, 0);
                    #pragma unroll
                    for (int rr = 0; rr < 4; ++rr)
                        accT[m][nt][rr] += tb[m][rr] * D[rr];
                }
            }
        }
    }

    // ---- Phase C: ii1 = tanh(i1_1 @ ii1_W + b) -> atomic p1n[idx_j] ----
    {
        const u16* gII = wb + OII1T;
        #pragma unroll
        for (int m = 0; m < 2; ++m) {
            #pragma unroll
            for (int nt = 0; nt < 2; ++nt)
                #pragma unroll
                for (int rr = 0; rr < 4; ++rr)
                    sT2[(4 * kg + rr) * 40 + 16 * nt + r16] = (u16)f2b(accT[m][nt][rr]);
            s8v av = *(const s8v*)(sT2 + r16 * 40 + 8 * kg);
            #pragma unroll
            for (int nt = 0; nt < 2; ++nt) {
                s8v bv = *(const s8v*)(gII + (nt * 64 + l) * 8);
                f4v ia = __builtin_amdgcn_mfma_f32_16x16x32_bf16(av, bv, zf, 0, 0, 0);
                #pragma unroll
                for (int rr = 0; rr < 4; ++rr) {
                    int rowD = m * 16 + 4 * kg + rr;
                    atomicAdd(&p1n[(size_t)sIdxJ[rowD] * 32 + 16 * nt + r16],
                              tanhf_fast(ia[rr] + vii1[nt]));
                }
            }
        }
    }

    // ---- stage Bl3 (16 KB) into sBl once; reused across all 3 d ----
    {
        const int4* gBl3v = (const int4*)(wb + OBL3G); // 1024 int4
        int4 t3[4];
        #pragma unroll
        for (int i = 0; i < 4; ++i) t3[i] = gBl3v[(w + 4 * i) * 64 + l];
        __syncthreads();                    // Phase-B readers of sBl done
        #pragma unroll
        for (int i = 0; i < 4; ++i) ((int4*)sBl)[(w + 4 * i) * 64 + l] = t3[i];
        __syncthreads();
    }

    // ---- Phase D: pi3 branch per Cartesian d ----
    const u16* gW13 = wb + OW1T3;
    const u16* gW23 = wb + OW2T3;
    const u16* gII3 = wb + OII3T;
    for (int d = 0; d < 3; ++d) {
        s8v avG2[2];
        #pragma unroll
        for (int m = 0; m < 2; ++m) {
            int rowA = m * 16 + r16;
            int ni = sIdxI[rowA], nj = sIdxJ[rowA];
            s8v av0 = *(const s8v*)(p3hb + ((size_t)ni * 3 + d) * 32 + kg * 8);
            s8v av1 = *(const s8v*)(p3hb + ((size_t)nj * 3 + d) * 32 + kg * 8);
            #pragma unroll
            for (int nt = 0; nt < 2; ++nt) {
                s8v bv0 = *(const s8v*)(gW13 + ((nt * 2 + 0) * 64 + l) * 8);
                s8v bv1 = *(const s8v*)(gW13 + ((nt * 2 + 1) * 64 + l) * 8);
                f4v g = __builtin_amdgcn_mfma_f32_16x16x32_bf16(av0, bv0, zf, 0, 0, 0);
                g = __builtin_amdgcn_mfma_f32_16x16x32_bf16(av1, bv1, g, 0, 0, 0);
                #pragma unroll
                for (int rr = 0; rr < 4; ++rr)
                    sT2[(4 * kg + rr) * 40 + 16 * nt + r16] = (u16)f2b(g[rr] + vb13[nt]);
            }
            s8v avg = *(const s8v*)(sT2 + r16 * 40 + 8 * kg);
            #pragma unroll
            for (int nt = 0; nt < 2; ++nt) {
                s8v bv = *(const s8v*)(gW23 + (nt * 64 + l) * 8);
                f4v g2 = __builtin_amdgcn_mfma_f32_16x16x32_bf16(avg, bv, zf, 0, 0, 0);
                #pragma unroll
                for (int rr = 0; rr < 4; ++rr)
                    sT2[(4 * kg + rr) * 40 + 16 * nt + r16] = (u16)f2b(g2[rr] + vb23[nt]);
            }
            avG2[m] = *(const s8v*)(sT2 + r16 * 40 + 8 * kg);
        }
        // W33 b-form from LDS-staged Bl3
        f4v accP[2][2];
        #pragma unroll
        for (int m = 0; m < 2; ++m) { accP[m][0] = zf; accP[m][1] = zf; }
        #pragma unroll 2
        for (int b = 0; b < 8; ++b) {
            float tb[2][4];
            #pragma unroll
            for (int m = 0; m < 2; ++m)
                #pragma unroll
                for (int rr = 0; rr < 4; ++rr)
                    tb[m][rr] = sBasT[b * 32 + m * 16 + 4 * kg + rr];
            #pragma unroll
            for (int nt = 0; nt < 2; ++nt) {
                s8v bv = *(const s8v*)(sBl + ((b * 2 + nt) * 64 + l) * 8);
                #pragma unroll
                for (int m = 0; m < 2; ++m) {
                    f4v D = __builtin_amdgcn_mfma_f32_16x16x32_bf16(avG2[m], bv, zf, 0, 0, 0);
                    #pragma unroll
                    for (int rr = 0; rr < 4; ++rr)
                        accP[m][nt][rr] += tb[m][rr] * D[rr];
                }
            }
        }
        // ii3 + combine + atomic p3n
        #pragma unroll
        for (int m = 0; m < 2; ++m) {
            #pragma unroll
            for (int nt = 0; nt < 2; ++nt)
                #pragma unroll
                for (int rr = 0; rr < 4; ++rr)
                    sT2[(4 * kg + rr) * 40 + 16 * nt + r16] = (u16)f2b(accP[m][nt][rr]);
            s8v av = *(const s8v*)(sT2 + r16 * 40 + 8 * kg);
            #pragma unroll
            for (int nt = 0; nt < 2; ++nt) {
                s8v bv = *(const s8v*)(gII3 + (nt * 64 + l) * 8);
                f4v ja = __builtin_amdgcn_mfma_f32_16x16x32_bf16(av, bv, zf, 0, 0, 0);
                #pragma unroll
                for (int rr = 0; rr < 4; ++rr) {
                    int rowD = m * 16 + 4 * kg + rr;
                    float i3a = tanhf_fast(ja[rr] + vii3[nt]);
                    float val = i3a * accT[m][2 + nt][rr] + sR3[d * 32 + rowD] * accT[m][4 + nt][rr];
                    atomicAdd(&p3n[((size_t)sIdxJ[rowD] * 3 + d) * 32 + 16 * nt + r16], val);
                }
            }
        }
    }
}

// ---------------- finalize: p1o = sum_d p3n^2 + p1n ; p3o = p3n * p1o -----
__global__ __launch_bounds__(256) void finalize_kernel(
    const float* __restrict__ p1n, const float* __restrict__ p3n,
    float* __restrict__ out)
{
    int t = blockIdx.x * 256 + threadIdx.x;
    int n = t >> 5, c = t & 31;
    float a0 = p3n[(n * 3 + 0) * 32 + c];
    float a1 = p3n[(n * 3 + 1) * 32 + c];
    float a2 = p3n[(n * 3 + 2) * 32 + c];
    float p1o = p1n[t] + a0 * a0 + a1 * a1 + a2 * a2;
    out[t] = p1o;
    float* o3 = out + NN * 32;
    o3[(n * 3 + 0) * 32 + c] = a0 * p1o;
    o3[(n * 3 + 1) * 32 + c] = a1 * p1o;
    o3[(n * 3 + 2) * 32 + c] = a2 * p1o;
}

extern "C" void kernel_launch(void* const* d_in, const int* in_sizes, int n_in,
                              void* d_out, int out_size, void* d_ws, size_t ws_size,
                              hipStream_t stream) {
    const float* p1     = (const float*)d_in[0];
    const float* p3     = (const float*)d_in[1];
    const float* r3     = (const float*)d_in[2];
    const float* basis  = (const float*)d_in[3];
    const int*   idx_i  = (const int*)d_in[4];
    const int*   idx_j  = (const int*)d_in[5];
    const float* pp1_W  = (const float*)d_in[6];
    const float* pp1_b  = (const float*)d_in[7];
    const float* pi1_W1 = (const float*)d_in[8];
    const float* pi1_b1 = (const float*)d_in[9];
    const float* pi1_W2 = (const float*)d_in[10];
    const float* pi1_b2 = (const float*)d_in[11];
    const float* pi1_W3 = (const float*)d_in[12];
    const float* ii1_W  = (const float*)d_in[13];
    const float* ii1_b  = (const float*)d_in[14];
    const float* pp3_W  = (const float*)d_in[15];
    const float* pp3_b  = (const float*)d_in[16];
    const float* pi3_W1 = (const float*)d_in[17];
    const float* pi3_b1 = (const float*)d_in[18];
    const float* pi3_W2 = (const float*)d_in[19];
    const float* pi3_b2 = (const float*)d_in[20];
    const float* pi3_W3 = (const float*)d_in[21];
    const float* ii3_W  = (const float*)d_in[22];
    const float* ii3_b  = (const float*)d_in[23];

    char* ws = (char*)d_ws;
    u16*   p1hb = (u16*)(ws + OFF_P1HB);
    u16*   p3hb = (u16*)(ws + OFF_P3HB);
    u16*   wb   = (u16*)(ws + OFF_WB);
    float* p1n  = (float*)(ws + OFF_P1N);
    float* p3n  = (float*)(ws + OFF_P3N);

    hipMemsetAsync(p1n, 0, 5120000, stream);

    node_prep<<<dim3(5000), dim3(256), 0, stream>>>(p1, p3, pp1_W, pp1_b, pp3_W, pp3_b, p1hb, p3hb);
    wprep<<<dim3(NWB / 256), dim3(256), 0, stream>>>(
        pi1_W1, pi1_W2, pi1_W3, ii1_W, pi3_W1, pi3_W2, pi3_W3, ii3_W, wb);

    edge_kernel<<<dim3(NE / 128), dim3(256), 0, stream>>>(
        p1hb, p3hb, r3, basis, idx_i, idx_j, wb,
        pi1_b1, pi1_b2, ii1_b, pi3_b1, pi3_b2, ii3_b,
        p1n, p3n);

    finalize_kernel<<<dim3(1250), dim3(256), 0, stream>>>(p1n, p3n, (float*)d_out);
}

// Round 14
// 129.709 us; speedup vs baseline: 1.2728x; 1.2728x over previous
//
#include <hip/hip_runtime.h>
#include <math.h>

#define NN 10000
#define NE 160000

typedef __attribute__((ext_vector_type(8))) short s8v;
typedef __attribute__((ext_vector_type(4))) float f4v;
typedef unsigned short u16;

// ---- ws byte layout ----
#define OFF_P1HB 0u          // N*32 bf16      = 640000 B
#define OFF_P3HB 640000u     // N*3*32 bf16    = 1920000 B
#define OFF_WB   2560000u    // NWB bf16       = 184320 B
#define OFF_P1N  2764800u    // N*32 f32       = 1280000 B
#define OFF_P3N  4044800u    // N*3*32 f32     = 3840000 B

// ---- wb (ushort element) offsets: ALL tables in per-lane consumption order
// [..][lane 64][8 u16] -> every wave B-load is one contiguous 1KB read. ----
#define OW1T1 0       // [nt2][ks2][64][8]  = 2048
#define OW2T1 2048    // [nt6][64][8]       = 3072
#define OII1T 5120    // [nt2][64][8]       = 1024
#define OW1T3 6144    // [nt2][ks2][64][8]  = 2048
#define OW2T3 8192    // [nt2][64][8]       = 1024
#define OII3T 9216    // [nt2][64][8]       = 1024
#define OBLG  10240   // [b8][nt6][ks3][64][8] = 73728
#define OBL3G 83968   // [b8][nt2][64][8]   = 8192
#define NWB   92160

__device__ __forceinline__ short f2b(float f) {
    unsigned u = __float_as_uint(f);
    u += 0x7fffu + ((u >> 16) & 1u);
    return (short)(u >> 16);
}
__device__ __forceinline__ float tanhf_fast(float x) {
    float xc = fminf(9.f, fmaxf(-9.f, x));
    float e = __expf(2.f * xc);
    return (e - 1.f) * __builtin_amdgcn_rcpf(e + 1.f);
}

// ---------------- node prep: p1h/p3h = tanh(x@W+b) -> bf16 ----------------
__global__ __launch_bounds__(256) void node_prep(
    const float* __restrict__ p1, const float* __restrict__ p3,
    const float* __restrict__ pp1_W, const float* __restrict__ pp1_b,
    const float* __restrict__ pp3_W, const float* __restrict__ pp3_b,
    u16* __restrict__ p1hb, u16* __restrict__ p3hb)
{
    __shared__ float Ws[2][32 * 32];
    __shared__ float bsm[2][32];
    int tid = threadIdx.x;
    for (int i = tid; i < 32 * 32; i += 256) { Ws[0][i] = pp1_W[i]; Ws[1][i] = pp3_W[i]; }
    if (tid < 32) { bsm[0][tid] = pp1_b[tid]; bsm[1][tid] = pp3_b[tid]; }
    __syncthreads();
    int idx = blockIdx.x * 256 + tid;
    int n = idx >> 7;
    int r = (idx >> 5) & 3;
    int c = idx & 31;
    int sel = (r == 0) ? 0 : 1;
    const float* in = (r == 0) ? (p1 + n * 32) : (p3 + (n * 3 + (r - 1)) * 32);
    float acc = bsm[sel][c];
    #pragma unroll
    for (int k = 0; k < 32; ++k) acc += in[k] * Ws[sel][k * 32 + c];
    short v = f2b(tanhf(acc));
    if (r == 0) p1hb[n * 32 + c] = (u16)v;
    else        p3hb[(n * 3 + (r - 1)) * 32 + c] = (u16)v;
}

// -------- weight prep: bf16 + per-lane-consumption-order layout -----------
__global__ __launch_bounds__(256) void wprep(
    const float* __restrict__ W1, const float* __restrict__ W2,
    const float* __restrict__ W3, const float* __restrict__ ii1,
    const float* __restrict__ W13, const float* __restrict__ W23,
    const float* __restrict__ W33, const float* __restrict__ ii3,
    u16* __restrict__ wb)
{
    int i0 = blockIdx.x * 256 + threadIdx.x;
    if (i0 >= NWB) return;
    int i = i0;
    float v;
    if (i < 2048) {
        int j = i & 7, L = (i >> 3) & 63, ks = (i >> 9) & 1, nt = i >> 10;
        v = W1[(ks * 32 + (L >> 4) * 8 + j) * 32 + 16 * nt + (L & 15)];
    } else if ((i -= 2048) < 3072) {
        int j = i & 7, L = (i >> 3) & 63, nt = i >> 9;
        v = W2[((L >> 4) * 8 + j) * 96 + 16 * nt + (L & 15)];
    } else if ((i -= 3072) < 1024) {
        int j = i & 7, L = (i >> 3) & 63, nt = i >> 9;
        v = ii1[((L >> 4) * 8 + j) * 32 + 16 * nt + (L & 15)];
    } else if ((i -= 1024) < 2048) {
        int j = i & 7, L = (i >> 3) & 63, ks = (i >> 9) & 1, nt = i >> 10;
        v = W13[(ks * 32 + (L >> 4) * 8 + j) * 32 + 16 * nt + (L & 15)];
    } else if ((i -= 2048) < 1024) {
        int j = i & 7, L = (i >> 3) & 63, nt = i >> 9;
        v = W23[((L >> 4) * 8 + j) * 32 + 16 * nt + (L & 15)];
    } else if ((i -= 1024) < 1024) {
        int j = i & 7, L = (i >> 3) & 63, nt = i >> 9;
        v = ii3[((L >> 4) * 8 + j) * 32 + 16 * nt + (L & 15)];
    } else if ((i -= 1024) < 73728) {
        int b = i / 9216, r = i % 9216;
        int nt = r / 1536, r2 = r % 1536;
        int ks = r2 / 512, r3 = r2 & 511;
        int L = r3 >> 3, j = r3 & 7;
        v = W3[(ks * 32 + (L >> 4) * 8 + j) * 768 + (16 * nt + (L & 15)) * 8 + b];
    } else {
        i -= 73728;
        int b = i >> 10, r = i & 1023;
        int nt = r >> 9, r3 = r & 511;
        int L = r3 >> 3, j = r3 & 7;
        v = W33[((L >> 4) * 8 + j) * 256 + (16 * nt + (L & 15)) * 8 + b];
    }
    wb[i0] = (u16)f2b(v);
}

// ------- fused edge kernel: 32 edges per 1-wave block (2 M-tiles) ---------
// Round-10 structure exactly (best so far: 124 us edge) + coalesced weight
// layout only. Every B-load: 64 lanes x 16B contiguous = 1KB, line-aligned.
__global__ __launch_bounds__(64, 3) void edge_kernel(
    const u16* __restrict__ p1hb, const u16* __restrict__ p3hb,
    const float* __restrict__ r3, const float* __restrict__ basis,
    const int* __restrict__ idx_i, const int* __restrict__ idx_j,
    const u16* __restrict__ wb,
    const float* __restrict__ b1, const float* __restrict__ b2,
    const float* __restrict__ ii1b,
    const float* __restrict__ b13, const float* __restrict__ b23,
    const float* __restrict__ ii3b,
    float* __restrict__ p1n, float* __restrict__ p3n)
{
    // 6.3 KB LDS, single wave per block
    __shared__ int4 smem4[400];
    char* sw = (char*)smem4;
    int*   sIdxI = (int*)(sw + 0);       // [32]
    int*   sIdxJ = (int*)(sw + 128);     // [32]
    float* sBasT = (float*)(sw + 256);   // [8][32] transposed basis
    float* sR3   = (float*)(sw + 1280);  // [3][32]
    u16*   sT1   = (u16*)(sw + 1664);    // [16][104] h2 transpose buffer
    u16*   sT2   = (u16*)(sw + 4992);    // [16][40]  small transpose buffer

    const int l   = threadIdx.x & 63;
    const int r16 = l & 15;
    const int kg  = l >> 4;
    const int ebase = blockIdx.x * 32;

    // ---- staging (single wave: in-order LDS, no barriers) ----
    if (l < 32) sIdxI[l] = idx_i[ebase + l];
    else        sIdxJ[l - 32] = idx_j[ebase + l - 32];
    {
        int e = l & 31, hf = l >> 5;
        const float4* bp = (const float4*)(basis + (size_t)(ebase + e) * 8);
        float4 q = bp[hf];
        sBasT[(4 * hf + 0) * 32 + e] = q.x;
        sBasT[(4 * hf + 1) * 32 + e] = q.y;
        sBasT[(4 * hf + 2) * 32 + e] = q.z;
        sBasT[(4 * hf + 3) * 32 + e] = q.w;
        if (hf == 0) {
            sR3[e]      = r3[(size_t)(ebase + e) * 3 + 0];
            sR3[32 + e] = r3[(size_t)(ebase + e) * 3 + 1];
            sR3[64 + e] = r3[(size_t)(ebase + e) * 3 + 2];
        }
    }

    // bias registers (per-lane channel slices)
    const float vb1[2]  = { b1[r16],   b1[16 + r16] };
    float vb2[6];
    #pragma unroll
    for (int nt = 0; nt < 6; ++nt) vb2[nt] = b2[16 * nt + r16];
    const float vii1[2] = { ii1b[r16], ii1b[16 + r16] };
    const float vb13[2] = { b13[r16],  b13[16 + r16] };
    const float vb23[2] = { b23[r16],  b23[16 + r16] };
    const float vii3[2] = { ii3b[r16], ii3b[16 + r16] };

    const f4v zf = {0.f, 0.f, 0.f, 0.f};

    // ---- Phase A: per M-tile pi1 front (h1 -> h2 -> af regs) ----
    s8v af[2][3];
    f4v accT[2][6];
    #pragma unroll
    for (int m = 0; m < 2; ++m)
        #pragma unroll
        for (int nt = 0; nt < 6; ++nt) accT[m][nt] = zf;

    const u16* gW1 = wb + OW1T1;
    const u16* gW2 = wb + OW2T1;
    #pragma unroll
    for (int m = 0; m < 2; ++m) {
        int rowA = m * 16 + r16;
        int ni = sIdxI[rowA], nj = sIdxJ[rowA];
        s8v av0 = *(const s8v*)(p1hb + (size_t)ni * 32 + kg * 8);
        s8v av1 = *(const s8v*)(p1hb + (size_t)nj * 32 + kg * 8);
        #pragma unroll
        for (int nt = 0; nt < 2; ++nt) {
            s8v bv0 = *(const s8v*)(gW1 + ((nt * 2 + 0) * 64 + l) * 8);
            s8v bv1 = *(const s8v*)(gW1 + ((nt * 2 + 1) * 64 + l) * 8);
            f4v a = __builtin_amdgcn_mfma_f32_16x16x32_bf16(av0, bv0, zf, 0, 0, 0);
            a = __builtin_amdgcn_mfma_f32_16x16x32_bf16(av1, bv1, a, 0, 0, 0);
            #pragma unroll
            for (int rr = 0; rr < 4; ++rr)
                sT2[(4 * kg + rr) * 40 + 16 * nt + r16] = (u16)f2b(a[rr] + vb1[nt]);
        }
        s8v av2 = *(const s8v*)(sT2 + r16 * 40 + 8 * kg);
        #pragma unroll
        for (int nt = 0; nt < 6; ++nt) {
            s8v bv = *(const s8v*)(gW2 + (nt * 64 + l) * 8);
            f4v acc = __builtin_amdgcn_mfma_f32_16x16x32_bf16(av2, bv, zf, 0, 0, 0);
            #pragma unroll
            for (int rr = 0; rr < 4; ++rr)
                sT1[(4 * kg + rr) * 104 + 16 * nt + r16] = (u16)f2b(acc[rr] + vb2[nt]);
        }
        af[m][0] = *(const s8v*)(sT1 + r16 * 104 + 8 * kg);
        af[m][1] = *(const s8v*)(sT1 + r16 * 104 + 32 + 8 * kg);
        af[m][2] = *(const s8v*)(sT1 + r16 * 104 + 64 + 8 * kg);
    }

    // ---- Phase B: pi1-W3 b-form, B reused across 2 M-tiles ----
    {
        const u16* gBl = wb + OBLG;
        #pragma unroll 2
        for (int b = 0; b < 8; ++b) {
            float tb[2][4];
            #pragma unroll
            for (int m = 0; m < 2; ++m)
                #pragma unroll
                for (int rr = 0; rr < 4; ++rr)
                    tb[m][rr] = sBasT[b * 32 + m * 16 + 4 * kg + rr];
            #pragma unroll
            for (int nt = 0; nt < 6; ++nt) {
                const u16* bp = gBl + (((size_t)b * 6 + nt) * 3) * 512 + l * 8;
                s8v bv0 = *(const s8v*)(bp);
                s8v bv1 = *(const s8v*)(bp + 512);
                s8v bv2 = *(const s8v*)(bp + 1024);
                #pragma unroll
                for (int m = 0; m < 2; ++m) {
                    f4v D = __builtin_amdgcn_mfma_f32_16x16x32_bf16(af[m][0], bv0, zf, 0, 0, 0);
                    D = __builtin_amdgcn_mfma_f32_16x16x32_bf16(af[m][1], bv1, D, 0, 0, 0);
                    D = __builtin_amdgcn_mfma_f32_16x16x32_bf16(af[m][2], bv2, D, 0, 0, 0);
                    #pragma unroll
                    for (int rr = 0; rr < 4; ++rr)
                        accT[m][nt][rr] += tb[m][rr] * D[rr];
                }
            }
        }
    }

    // ---- Phase C: ii1 = tanh(i1_1 @ ii1_W + b) -> atomic p1n[idx_j] ----
    {
        const u16* gII = wb + OII1T;
        #pragma unroll
        for (int m = 0; m < 2; ++m) {
            #pragma unroll
            for (int nt = 0; nt < 2; ++nt)
                #pragma unroll
                for (int rr = 0; rr < 4; ++rr)
                    sT2[(4 * kg + rr) * 40 + 16 * nt + r16] = (u16)f2b(accT[m][nt][rr]);
            s8v av = *(const s8v*)(sT2 + r16 * 40 + 8 * kg);
            #pragma unroll
            for (int nt = 0; nt < 2; ++nt) {
                s8v bv = *(const s8v*)(gII + (nt * 64 + l) * 8);
                f4v ia = __builtin_amdgcn_mfma_f32_16x16x32_bf16(av, bv, zf, 0, 0, 0);
                #pragma unroll
                for (int rr = 0; rr < 4; ++rr) {
                    int rowD = m * 16 + 4 * kg + rr;
                    atomicAdd(&p1n[(size_t)sIdxJ[rowD] * 32 + 16 * nt + r16],
                              tanhf_fast(ia[rr] + vii1[nt]));
                }
            }
        }
    }

    // ---- Phase D: pi3 branch per Cartesian d ----
    const u16* gW13 = wb + OW1T3;
    const u16* gW23 = wb + OW2T3;
    const u16* gII3 = wb + OII3T;
    const u16* gBl3 = wb + OBL3G;
    for (int d = 0; d < 3; ++d) {
        s8v avG2[2];
        #pragma unroll
        for (int m = 0; m < 2; ++m) {
            int rowA = m * 16 + r16;
            int ni = sIdxI[rowA], nj = sIdxJ[rowA];
            s8v av0 = *(const s8v*)(p3hb + ((size_t)ni * 3 + d) * 32 + kg * 8);
            s8v av1 = *(const s8v*)(p3hb + ((size_t)nj * 3 + d) * 32 + kg * 8);
            #pragma unroll
            for (int nt = 0; nt < 2; ++nt) {
                s8v bv0 = *(const s8v*)(gW13 + ((nt * 2 + 0) * 64 + l) * 8);
                s8v bv1 = *(const s8v*)(gW13 + ((nt * 2 + 1) * 64 + l) * 8);
                f4v g = __builtin_amdgcn_mfma_f32_16x16x32_bf16(av0, bv0, zf, 0, 0, 0);
                g = __builtin_amdgcn_mfma_f32_16x16x32_bf16(av1, bv1, g, 0, 0, 0);
                #pragma unroll
                for (int rr = 0; rr < 4; ++rr)
                    sT2[(4 * kg + rr) * 40 + 16 * nt + r16] = (u16)f2b(g[rr] + vb13[nt]);
            }
            s8v avg = *(const s8v*)(sT2 + r16 * 40 + 8 * kg);
            #pragma unroll
            for (int nt = 0; nt < 2; ++nt) {
                s8v bv = *(const s8v*)(gW23 + (nt * 64 + l) * 8);
                f4v g2 = __builtin_amdgcn_mfma_f32_16x16x32_bf16(avg, bv, zf, 0, 0, 0);
                #pragma unroll
                for (int rr = 0; rr < 4; ++rr)
                    sT2[(4 * kg + rr) * 40 + 16 * nt + r16] = (u16)f2b(g2[rr] + vb23[nt]);
            }
            avG2[m] = *(const s8v*)(sT2 + r16 * 40 + 8 * kg);
        }
        // W33 b-form with 2-M reuse
        f4v accP[2][2];
        #pragma unroll
        for (int m = 0; m < 2; ++m) { accP[m][0] = zf; accP[m][1] = zf; }
        #pragma unroll 2
        for (int b = 0; b < 8; ++b) {
            float tb[2][4];
            #pragma unroll
            for (int m = 0; m < 2; ++m)
                #pragma unroll
                for (int rr = 0; rr < 4; ++rr)
                    tb[m][rr] = sBasT[b * 32 + m * 16 + 4 * kg + rr];
            #pragma unroll
            for (int nt = 0; nt < 2; ++nt) {
                s8v bv = *(const s8v*)(gBl3 + (((size_t)b * 2 + nt) * 64 + l) * 8);
                #pragma unroll
                for (int m = 0; m < 2; ++m) {
                    f4v D = __builtin_amdgcn_mfma_f32_16x16x32_bf16(avG2[m], bv, zf, 0, 0, 0);
                    #pragma unroll
                    for (int rr = 0; rr < 4; ++rr)
                        accP[m][nt][rr] += tb[m][rr] * D[rr];
                }
            }
        }
        // ii3 + combine + atomic p3n
        #pragma unroll
        for (int m = 0; m < 2; ++m) {
            #pragma unroll
            for (int nt = 0; nt < 2; ++nt)
                #pragma unroll
                for (int rr = 0; rr < 4; ++rr)
                    sT2[(4 * kg + rr) * 40 + 16 * nt + r16] = (u16)f2b(accP[m][nt][rr]);
            s8v av = *(const s8v*)(sT2 + r16 * 40 + 8 * kg);
            #pragma unroll
            for (int nt = 0; nt < 2; ++nt) {
                s8v bv = *(const s8v*)(gII3 + (nt * 64 + l) * 8);
                f4v ja = __builtin_amdgcn_mfma_f32_16x16x32_bf16(av, bv, zf, 0, 0, 0);
                #pragma unroll
                for (int rr = 0; rr < 4; ++rr) {
                    int rowD = m * 16 + 4 * kg + rr;
                    float i3a = tanhf_fast(ja[rr] + vii3[nt]);
                    float val = i3a * accT[m][2 + nt][rr] + sR3[d * 32 + rowD] * accT[m][4 + nt][rr];
                    atomicAdd(&p3n[((size_t)sIdxJ[rowD] * 3 + d) * 32 + 16 * nt + r16], val);
                }
            }
        }
    }
}

// ---------------- finalize: p1o = sum_d p3n^2 + p1n ; p3o = p3n * p1o -----
__global__ __launch_bounds__(256) void finalize_kernel(
    const float* __restrict__ p1n, const float* __restrict__ p3n,
    float* __restrict__ out)
{
    int t = blockIdx.x * 256 + threadIdx.x;
    int n = t >> 5, c = t & 31;
    float a0 = p3n[(n * 3 + 0) * 32 + c];
    float a1 = p3n[(n * 3 + 1) * 32 + c];
    float a2 = p3n[(n * 3 + 2) * 32 + c];
    float p1o = p1n[t] + a0 * a0 + a1 * a1 + a2 * a2;
    out[t] = p1o;
    float* o3 = out + NN * 32;
    o3[(n * 3 + 0) * 32 + c] = a0 * p1o;
    o3[(n * 3 + 1) * 32 + c] = a1 * p1o;
    o3[(n * 3 + 2) * 32 + c] = a2 * p1o;
}

extern "C" void kernel_launch(void* const* d_in, const int* in_sizes, int n_in,
                              void* d_out, int out_size, void* d_ws, size_t ws_size,
                              hipStream_t stream) {
    const float* p1     = (const float*)d_in[0];
    const float* p3     = (const float*)d_in[1];
    const float* r3     = (const float*)d_in[2];
    const float* basis  = (const float*)d_in[3];
    const int*   idx_i  = (const int*)d_in[4];
    const int*   idx_j  = (const int*)d_in[5];
    const float* pp1_W  = (const float*)d_in[6];
    const float* pp1_b  = (const float*)d_in[7];
    const float* pi1_W1 = (const float*)d_in[8];
    const float* pi1_b1 = (const float*)d_in[9];
    const float* pi1_W2 = (const float*)d_in[10];
    const float* pi1_b2 = (const float*)d_in[11];
    const float* pi1_W3 = (const float*)d_in[12];
    const float* ii1_W  = (const float*)d_in[13];
    const float* ii1_b  = (const float*)d_in[14];
    const float* pp3_W  = (const float*)d_in[15];
    const float* pp3_b  = (const float*)d_in[16];
    const float* pi3_W1 = (const float*)d_in[17];
    const float* pi3_b1 = (const float*)d_in[18];
    const float* pi3_W2 = (const float*)d_in[19];
    const float* pi3_b2 = (const float*)d_in[20];
    const float* pi3_W3 = (const float*)d_in[21];
    const float* ii3_W  = (const float*)d_in[22];
    const float* ii3_b  = (const float*)d_in[23];

    char* ws = (char*)d_ws;
    u16*   p1hb = (u16*)(ws + OFF_P1HB);
    u16*   p3hb = (u16*)(ws + OFF_P3HB);
    u16*   wb   = (u16*)(ws + OFF_WB);
    float* p1n  = (float*)(ws + OFF_P1N);
    float* p3n  = (float*)(ws + OFF_P3N);

    hipMemsetAsync(p1n, 0, 5120000, stream);

    node_prep<<<dim3(5000), dim3(256), 0, stream>>>(p1, p3, pp1_W, pp1_b, pp3_W, pp3_b, p1hb, p3hb);
    wprep<<<dim3(NWB / 256), dim3(256), 0, stream>>>(
        pi1_W1, pi1_W2, pi1_W3, ii1_W, pi3_W1, pi3_W2, pi3_W3, ii3_W, wb);

    edge_kernel<<<dim3(NE / 32), dim3(64), 0, stream>>>(
        p1hb, p3hb, r3, basis, idx_i, idx_j, wb,
        pi1_b1, pi1_b2, ii1_b, pi3_b1, pi3_b2, ii3_b,
        p1n, p3n);

    finalize_kernel<<<dim3(1250), dim3(256), 0, stream>>>(p1n, p3n, (float*)d_out);
}